// Round 4
// baseline (215.866 us; speedup 1.0000x reference)
//
#include <hip/hip_runtime.h>
#include <hip/hip_cooperative_groups.h>

namespace cg = cooperative_groups;

#define BATCH 8192
#define NF 1024
#define NS 50000
#define MOM 0.2f

#define NTHR 256
#define NBLK 768                 // 3 blocks/CU on 256 CUs -> co-resident
#define CHAIN_BLKS 256
#define COPY_BLKS (NBLK - CHAIN_BLKS)            // 512
#define ROWS 4
#define NGROUPS (NS / ROWS)                      // 12500 groups of 4 rows
#define CHAIN_GPB 15                             // copy groups per chain block
#define CHAIN_GROUPS (CHAIN_BLKS * CHAIN_GPB)    // 3840
#define COPY_GROUPS (NGROUPS - CHAIN_GROUPS)     // 8660

__device__ __forceinline__ void copy_group(const float4* __restrict__ src,
                                           float4* __restrict__ dst,
                                           int g, int tid) {
    // one group = 4 consecutive rows = 1024 float4, block covers it in 4 strides
    const size_t base = (size_t)g * (ROWS * NF / 4) + tid;
    const float4 v0 = src[base];
    const float4 v1 = src[base + 256];
    const float4 v2 = src[base + 512];
    const float4 v3 = src[base + 768];
    dst[base]       = v0;
    dst[base + 256] = v1;
    dst[base + 512] = v2;
    dst[base + 768] = v3;
}

__global__ __launch_bounds__(NTHR, 3)
void fused_all(const float* __restrict__ f_out,
               const float* __restrict__ features,
               const int* __restrict__ labels,
               int* __restrict__ heads,
               int* __restrict__ nxt,
               float* __restrict__ out)
{
    const int tid = threadIdx.x;
    const int bid = blockIdx.x;
    const float4* feat4 = reinterpret_cast<const float4*>(features);
    const float4* fout4 = reinterpret_cast<const float4*>(f_out);
    float4* out4 = reinterpret_cast<float4*>(out);

    __shared__ int s_labels[BATCH];   // 32 KB
    __shared__ int s_e[4], s_n[4];
    __shared__ float s_part[4];

    // ---------------- Phase A: chain-build (256 blocks) || bulk copy ------
    if (bid < CHAIN_BLKS) {
        for (int j = tid; j < BATCH; j += NTHR) s_labels[j] = labels[j];
        __syncthreads();
        #pragma unroll 1
        for (int k = 0; k < BATCH / CHAIN_BLKS; ++k) {   // 32 batch slots/block
            const int i = bid + CHAIN_BLKS * k;
            const int y = s_labels[i];
            int earlier = 0;
            int nx = 0x7fffffff;
            for (int j = tid; j < BATCH; j += NTHR) {
                const int lj = s_labels[j];
                if (lj == y && j != i) {
                    if (j < i) earlier = 1;
                    else nx = min(nx, j);
                }
            }
            for (int off = 32; off; off >>= 1) {
                earlier |= __shfl_xor(earlier, off, 64);
                nx = min(nx, __shfl_xor(nx, off, 64));
            }
            if ((tid & 63) == 0) { s_e[tid >> 6] = earlier; s_n[tid >> 6] = nx; }
            __syncthreads();
            if (tid == 0) {
                const int e = s_e[0] | s_e[1] | s_e[2] | s_e[3];
                const int n = min(min(s_n[0], s_n[1]), min(s_n[2], s_n[3]));
                heads[i] = !e;
                nxt[i]   = (n == 0x7fffffff) ? -1 : n;
            }
            __syncthreads();   // protect s_e/s_n before next slot
        }
        // join the copy: this block's static share of groups
        for (int k = 0; k < CHAIN_GPB; ++k)
            copy_group(feat4, out4, COPY_GROUPS + bid + CHAIN_BLKS * k, tid);
    } else {
        const int cb = bid - CHAIN_BLKS;
        for (int g = cb; g < COPY_GROUPS; g += COPY_BLKS)
            copy_group(feat4, out4, g, tid);
    }

    cg::this_grid().sync();

    // ---------------- Phase B: walk duplicate chains, overwrite rows ------
    const float m = MOM, om = 1.0f - MOM;
    for (int i = bid; i < BATCH; i += NBLK) {
        if (!heads[i]) continue;               // block-uniform
        const int y = labels[i];
        float4 v = feat4[(size_t)y * (NF / 4) + tid];
        int j = i;
        while (j >= 0) {
            const float4 x = fout4[(size_t)j * (NF / 4) + tid];
            v.x = m * v.x + om * x.x;
            v.y = m * v.y + om * x.y;
            v.z = m * v.z + om * x.z;
            v.w = m * v.w + om * x.w;
            float s = v.x * v.x + v.y * v.y + v.z * v.z + v.w * v.w;
            for (int off = 32; off; off >>= 1) s += __shfl_xor(s, off, 64);
            if ((tid & 63) == 0) s_part[tid >> 6] = s;
            __syncthreads();
            const float tot = s_part[0] + s_part[1] + s_part[2] + s_part[3];
            __syncthreads();
            const float inv = 1.0f / sqrtf(tot);
            v.x *= inv; v.y *= inv; v.z *= inv; v.w *= inv;
            j = nxt[j];
        }
        out4[(size_t)y * (NF / 4) + tid] = v;
    }
}

extern "C" void kernel_launch(void* const* d_in, const int* in_sizes, int n_in,
                              void* d_out, int out_size, void* d_ws, size_t ws_size,
                              hipStream_t stream) {
    const float* f_out    = (const float*)d_in[0];
    const float* features = (const float*)d_in[1];
    const int*   labels   = (const int*)d_in[2];
    float* out = (float*)d_out;

    int* heads = (int*)d_ws;            // BATCH ints
    int* nxt   = heads + BATCH;         // BATCH ints

    void* args[] = { (void*)&f_out, (void*)&features, (void*)&labels,
                     (void*)&heads, (void*)&nxt, (void*)&out };
    hipLaunchCooperativeKernel(reinterpret_cast<void*>(fused_all),
                               dim3(NBLK), dim3(NTHR), args, 0, stream);
}

// Round 5
// 104.550 us; speedup vs baseline: 2.0647x; 2.0647x over previous
//
#include <hip/hip_runtime.h>

#define BATCH 8192
#define NF 1024
#define NS 50000
#define MOM 0.2f

// ws layout: [first: NS ints][lastm: NS ints][nxt: BATCH ints]
// first/lastm are memset to 0x7F7F7F7F (large positive sentinel).
// lastm[y] holds min(BATCH-1-i) == BATCH-1-max(i), so one sentinel works for both.

// k1: 2 atomics per batch slot.
__global__ void build_firstlast(const int* __restrict__ labels,
                                int* __restrict__ first,
                                int* __restrict__ lastm) {
    const int i = blockIdx.x * blockDim.x + threadIdx.x;
    if (i >= BATCH) return;
    const int y = labels[i];
    atomicMin(&first[y], i);
    atomicMin(&lastm[y], BATCH - 1 - i);
}

// k2: one 64-lane wave per batch slot. Unique labels early-exit;
// duplicate-label slots (~1300) scan all 8192 labels for the next occurrence.
__global__ __launch_bounds__(64)
void build_next(const int* __restrict__ labels,
                const int* __restrict__ first,
                const int* __restrict__ lastm,
                int* __restrict__ nxt) {
    const int i = blockIdx.x;
    const int tid = threadIdx.x;
    const int y = labels[i];
    const int f = first[y];
    const int l = BATCH - 1 - lastm[y];
    if (f == l) {                 // unique occurrence
        if (tid == 0) nxt[i] = -1;
        return;
    }
    int nx = 0x7fffffff;
    for (int j = i + 1 + tid; j < BATCH; j += 64)
        if (labels[j] == y) nx = min(nx, j);
    for (int off = 32; off; off >>= 1)
        nx = min(nx, __shfl_xor(nx, off, 64));
    if (tid == 0) nxt[i] = (nx == 0x7fffffff) ? -1 : nx;
}

// One block per bank row y (256 threads x float4 = 1024 floats in registers).
// Untouched rows: straight copy. Touched rows: walk the duplicate chain,
// momentum-blend + block-reduced L2 normalize each step, write once.
__global__ __launch_bounds__(256)
void fused_bank(const float* __restrict__ f_out,
                const float* __restrict__ features,
                const int* __restrict__ first,
                const int* __restrict__ nxt,
                float* __restrict__ out) {
    const int y = blockIdx.x;
    const int tid = threadIdx.x;

    float4 v = reinterpret_cast<const float4*>(features + (size_t)y * NF)[tid];

    const int h = first[y];            // block-uniform; >= BATCH means untouched
    if (h < BATCH) {
        __shared__ float s_part[4];
        const float m = MOM, om = 1.0f - MOM;
        int j = h;
        while (j >= 0) {
            const float4 x = reinterpret_cast<const float4*>(f_out + (size_t)j * NF)[tid];
            v.x = m * v.x + om * x.x;
            v.y = m * v.y + om * x.y;
            v.z = m * v.z + om * x.z;
            v.w = m * v.w + om * x.w;
            float s = v.x * v.x + v.y * v.y + v.z * v.z + v.w * v.w;
            for (int off = 32; off; off >>= 1) s += __shfl_xor(s, off, 64);
            if ((tid & 63) == 0) s_part[tid >> 6] = s;
            __syncthreads();
            const float tot = s_part[0] + s_part[1] + s_part[2] + s_part[3];
            __syncthreads();  // protect s_part before next iteration overwrites
            const float inv = 1.0f / sqrtf(tot);
            v.x *= inv; v.y *= inv; v.z *= inv; v.w *= inv;
            j = nxt[j];
        }
    }
    reinterpret_cast<float4*>(out + (size_t)y * NF)[tid] = v;
}

extern "C" void kernel_launch(void* const* d_in, const int* in_sizes, int n_in,
                              void* d_out, int out_size, void* d_ws, size_t ws_size,
                              hipStream_t stream) {
    const float* f_out    = (const float*)d_in[0];
    const float* features = (const float*)d_in[1];
    const int*   labels   = (const int*)d_in[2];
    float* out = (float*)d_out;

    int* first = (int*)d_ws;            // NS ints
    int* lastm = first + NS;            // NS ints
    int* nxt   = lastm + NS;            // BATCH ints

    // sentinel-init first+lastm in one fill (0x7F7F7F7F is a large positive int)
    hipMemsetAsync(first, 0x7F, (size_t)2 * NS * sizeof(int), stream);

    build_firstlast<<<(BATCH + 255) / 256, 256, 0, stream>>>(labels, first, lastm);
    build_next<<<BATCH, 64, 0, stream>>>(labels, first, lastm, nxt);
    fused_bank<<<NS, 256, 0, stream>>>(f_out, features, first, nxt, out);
}

// Round 6
// 94.702 us; speedup vs baseline: 2.2794x; 1.1040x over previous
//
#include <hip/hip_runtime.h>

#define BATCH 8192
#define NF 1024
#define NS 50000
#define MOM 0.2f
#define MAXOCC 64   // max tracked occurrences of one label (random max ~4)

// ws layout: [first: NS ints][lastm: NS ints], memset to 0x7F7F7F7F.
// lastm[y] holds min(BATCH-1-i) == BATCH-1-max(i) so one sentinel serves both.
__global__ void build_firstlast(const int* __restrict__ labels,
                                int* __restrict__ first,
                                int* __restrict__ lastm) {
    const int i = blockIdx.x * blockDim.x + threadIdx.x;
    if (i >= BATCH) return;
    const int y = labels[i];
    atomicMin(&first[y], i);
    atomicMin(&lastm[y], BATCH - 1 - i);
}

// momentum blend + block-reduced L2 normalize (256 threads = 4 waves)
__device__ __forceinline__ void blend_normalize(float4& v, const float4 x,
                                                float* s_part, int tid) {
    const float m = MOM, om = 1.0f - MOM;
    v.x = m * v.x + om * x.x;
    v.y = m * v.y + om * x.y;
    v.z = m * v.z + om * x.z;
    v.w = m * v.w + om * x.w;
    float s = v.x * v.x + v.y * v.y + v.z * v.z + v.w * v.w;
    for (int off = 32; off; off >>= 1) s += __shfl_xor(s, off, 64);
    if ((tid & 63) == 0) s_part[tid >> 6] = s;
    __syncthreads();
    const float tot = s_part[0] + s_part[1] + s_part[2] + s_part[3];
    __syncthreads();   // protect s_part before any later reuse
    const float inv = 1.0f / sqrtf(tot);
    v.x *= inv; v.y *= inv; v.z *= inv; v.w *= inv;
}

// One block per bank row y. Untouched: straight copy. Single occurrence
// (the common touched case): one blend+normalize, no chain metadata.
// Multi-occurrence (~640 labels): block scans the 32KB label array itself,
// sorts the tiny occurrence list in LDS, applies updates in batch order.
__global__ __launch_bounds__(256)
void fused_bank(const float* __restrict__ f_out,
                const float* __restrict__ features,
                const int* __restrict__ labels,
                const int* __restrict__ first,
                const int* __restrict__ lastm,
                float* __restrict__ out) {
    const int y = blockIdx.x;
    const int tid = threadIdx.x;
    const float4* feat4 = reinterpret_cast<const float4*>(features);
    const float4* fout4 = reinterpret_cast<const float4*>(f_out);

    float4 v = feat4[(size_t)y * (NF / 4) + tid];

    const int h = first[y];            // block-uniform; >= BATCH means untouched
    if (h < BATCH) {
        __shared__ float s_part[4];
        const int l = BATCH - 1 - lastm[y];
        if (h == l) {
            // exactly one occurrence
            blend_normalize(v, fout4[(size_t)h * (NF / 4) + tid], s_part, tid);
        } else {
            // rare: collect all occurrences of y, in batch order
            __shared__ int s_cnt;
            __shared__ int s_idx[MAXOCC];
            if (tid == 0) s_cnt = 0;
            __syncthreads();
            for (int j = tid; j < BATCH; j += 256) {
                if (labels[j] == y) {
                    const int p = atomicAdd(&s_cnt, 1);
                    if (p < MAXOCC) s_idx[p] = j;
                }
            }
            __syncthreads();
            const int n = min(s_cnt, MAXOCC);
            if (tid == 0) {            // insertion-sort tiny list ascending
                for (int a = 1; a < n; ++a) {
                    const int key = s_idx[a];
                    int b = a - 1;
                    while (b >= 0 && s_idx[b] > key) { s_idx[b + 1] = s_idx[b]; --b; }
                    s_idx[b + 1] = key;
                }
            }
            __syncthreads();
            for (int t = 0; t < n; ++t)
                blend_normalize(v, fout4[(size_t)s_idx[t] * (NF / 4) + tid],
                                s_part, tid);
        }
    }
    reinterpret_cast<float4*>(out)[(size_t)y * (NF / 4) + tid] = v;
}

extern "C" void kernel_launch(void* const* d_in, const int* in_sizes, int n_in,
                              void* d_out, int out_size, void* d_ws, size_t ws_size,
                              hipStream_t stream) {
    const float* f_out    = (const float*)d_in[0];
    const float* features = (const float*)d_in[1];
    const int*   labels   = (const int*)d_in[2];
    float* out = (float*)d_out;

    int* first = (int*)d_ws;            // NS ints
    int* lastm = first + NS;            // NS ints

    hipMemsetAsync(first, 0x7F, (size_t)2 * NS * sizeof(int), stream);
    build_firstlast<<<(BATCH + 255) / 256, 256, 0, stream>>>(labels, first, lastm);
    fused_bank<<<NS, 256, 0, stream>>>(f_out, features, labels, first, lastm, out);
}